// Round 2
// baseline (250.593 us; speedup 1.0000x reference)
//
#include <hip/hip_runtime.h>

#define NB 16
#define NC 256
#define NHW 784
#define NATN 16
#define NM 12544          // 16*784
#define ND 256
#define NTRI 32896        // 256*257/2
#define ATT_OUT_OFF 526336
#define SPLITK 16

typedef float f32x4 __attribute__((ext_vector_type(4)));
typedef short bf16x8 __attribute__((ext_vector_type(8)));

static __device__ __forceinline__ unsigned short f2bf(float f) {
  unsigned int u = __float_as_uint(f);
  u = (u + 0x7FFFu + ((u >> 16) & 1u)) >> 16;   // RNE
  return (unsigned short)u;
}

#define GLD16(g, l) __builtin_amdgcn_global_load_lds(                      \
    (const __attribute__((address_space(1))) void*)(g),                    \
    (__attribute__((address_space(3))) void*)(l), 16, 0, 0)

// ---------------- z = (sigmoid(raw)+eps) * x  (bf16) + row sums; c==0 blocks emit att ----------------
__global__ __launch_bounds__(256)
void k_z(const float* __restrict__ x, const float* __restrict__ raw,
         unsigned short* __restrict__ z, float* __restrict__ s,
         float* __restrict__ out_att) {
  int bc = blockIdx.x;                 // b*256 + c
  int b  = bc >> 8;
  int c  = bc & 255;
  int t  = threadIdx.x;
  const float* xr = x + (size_t)bc * NHW;
  unsigned short* zr = z + (size_t)bc * NM;
  float sum = 0.f;
  if (t < 196) {
    float4 xv = ((const float4*)xr)[t];
    for (int a = 0; a < NATN; ++a) {
      const float* rr = raw + (size_t)(b * NATN + a) * NHW;
      float4 rv = ((const float4*)rr)[t];
      float a0 = 1.0f / (1.0f + __expf(-rv.x)) + 1e-12f;
      float a1 = 1.0f / (1.0f + __expf(-rv.y)) + 1e-12f;
      float a2 = 1.0f / (1.0f + __expf(-rv.z)) + 1e-12f;
      float a3 = 1.0f / (1.0f + __expf(-rv.w)) + 1e-12f;
      float v0 = a0 * xv.x, v1 = a1 * xv.y, v2 = a2 * xv.z, v3 = a3 * xv.w;
      ushort4 zv;
      zv.x = f2bf(v0); zv.y = f2bf(v1); zv.z = f2bf(v2); zv.w = f2bf(v3);
      *(ushort4*)&zr[a * NHW + t * 4] = zv;
      sum += v0 + v1 + v2 + v3;
      if (c == 0) {
        float4 av = make_float4(a0, a1, a2, a3);
        *(float4*)&out_att[(size_t)(b * NATN + a) * NHW + t * 4] = av;
      }
    }
  }
  for (int off = 32; off; off >>= 1) sum += __shfl_down(sum, off, 64);
  __shared__ float red[4];
  if ((t & 63) == 0) red[t >> 6] = sum;
  __syncthreads();
  if (t == 0) s[bc] = red[0] + red[1] + red[2] + red[3];
}

// ---------------- cov GEMM: P[split][b][t3] += z_tile * z_tile^T ----------------
// 128x128 tiles, BK=64, 4 waves, split-K=16 (12-13 ktiles each). Tiles (0,0),(0,1),(1,1).
// LDS XOR-swizzled via pre-swizzled global source (linear gload_lds dest).
__global__ __launch_bounds__(256)
void k_cov(const unsigned short* __restrict__ z, float* __restrict__ P) {
  int bid = blockIdx.x;
  int split = bid & 15;
  int t3 = (bid >> 4) % 3;
  int b = bid / 48;
  int tm = (t3 == 2) ? 1 : 0;
  int tn = (t3 >= 1) ? 1 : 0;

  __shared__ __align__(16) unsigned short As[128 * 64];
  __shared__ __align__(16) unsigned short Bs[128 * 64];

  int tid = threadIdx.x;
  int lane = tid & 63, w = tid >> 6;
  int wm = w >> 1, wn = w & 1;
  int fr = lane & 15, kg = lane >> 4;

  const unsigned short* zb = z + (size_t)b * NC * NM;
  int col8 = ((tid & 7) ^ ((tid >> 3) & 7)) * 8;       // source pre-swizzle
  const unsigned short* ab = zb + (size_t)(tm * 128 + (tid >> 3)) * NM + col8;
  const unsigned short* bb = zb + (size_t)(tn * 128 + (tid >> 3)) * NM + col8;

  f32x4 acc[4][4];
#pragma unroll
  for (int i = 0; i < 4; ++i)
#pragma unroll
    for (int j = 0; j < 4; ++j) acc[i][j] = f32x4{0.f, 0.f, 0.f, 0.f};

  int ktiles = 12 + (split < 4 ? 1 : 0);
  int k0 = (split * 12 + (split < 4 ? split : 4)) * 64;
  char* AsB = (char*)As + (size_t)w * 1024;
  char* BsB = (char*)Bs + (size_t)w * 1024;
  const char* Asc = (const char*)As;
  const char* Bsc = (const char*)Bs;

  for (int kt = 0; kt < ktiles; ++kt) {
    int kb = k0 + kt * 64;
#pragma unroll
    for (int r = 0; r < 4; ++r) GLD16(ab + (size_t)r * 32 * NM + kb, AsB + r * 4096);
#pragma unroll
    for (int r = 0; r < 4; ++r) GLD16(bb + (size_t)r * 32 * NM + kb, BsB + r * 4096);
    __syncthreads();
#pragma unroll
    for (int kk = 0; kk < 2; ++kk) {
      bf16x8 av[4], bv[4];
      int swz = (fr & 7) << 4;
#pragma unroll
      for (int fm = 0; fm < 4; ++fm)
        av[fm] = *(const bf16x8*)(Asc + (wm * 64 + fm * 16 + fr) * 128 + ((kk * 64 + kg * 16) ^ swz));
#pragma unroll
      for (int fn = 0; fn < 4; ++fn)
        bv[fn] = *(const bf16x8*)(Bsc + (wn * 64 + fn * 16 + fr) * 128 + ((kk * 64 + kg * 16) ^ swz));
#pragma unroll
      for (int fm = 0; fm < 4; ++fm)
#pragma unroll
        for (int fn = 0; fn < 4; ++fn)
          acc[fm][fn] = __builtin_amdgcn_mfma_f32_16x16x32_bf16(av[fm], bv[fn], acc[fm][fn], 0, 0, 0);
    }
    __syncthreads();
  }

  float* Pb = P + ((size_t)(split * NB + b) * 3 + t3) * 16384;
#pragma unroll
  for (int fm = 0; fm < 4; ++fm)
#pragma unroll
    for (int fn = 0; fn < 4; ++fn)
#pragma unroll
      for (int ri = 0; ri < 4; ++ri) {
        int row = wm * 64 + fm * 16 + kg * 4 + ri;   // tile-local
        int col = wn * 64 + fn * 16 + fr;
        Pb[row * 128 + col] = acc[fm][fn][ri];
      }
}

// ---------------- cov = (sum P)/M - s s^T / M^2 ; trace via atomicAdd ----------------
__global__ void k_asm(const float* __restrict__ P, const float* __restrict__ s,
                      float* __restrict__ cov, float* __restrict__ nrm) {
  int i = blockIdx.x * 256 + threadIdx.x;
  int b = i >> 16;
  int rc = i & 65535;
  int r = rc >> 8, c = rc & 255;
  int rr = r, cc = c;
  if (r >= 128 && c < 128) { rr = c; cc = r; }   // tile (1,0) -> mirror (0,1)
  int t3 = (rr >= 128) ? 2 : (cc >= 128 ? 1 : 0);
  int loc = (rr & 127) * 128 + (cc & 127);
  const float invM = 1.0f / 12544.0f;
  float g = 0.f;
#pragma unroll
  for (int sp = 0; sp < SPLITK; ++sp)
    g += P[((size_t)(sp * NB + b) * 3 + t3) * 16384 + loc];
  float v = g * invM - s[b * NC + r] * s[b * NC + c] * (invM * invM);
  cov[i] = v;
  if (r == c) atomicAdd(&nrm[b], v);
}

// ---------------- An = cov/normA (bf16); Z0 = 1.5I - 0.5 An (bf16) ----------------
__global__ void k_anzy(const float* __restrict__ cov, const float* __restrict__ nrm,
                       unsigned short* __restrict__ An, unsigned short* __restrict__ Z) {
  int i = blockIdx.x * 256 + threadIdx.x;
  int b = i >> 16;
  int rc = i & 65535;
  int r = rc >> 8, c = rc & 255;
  float a = cov[i] / nrm[b];
  An[i] = f2bf(a);
  Z[i]  = f2bf((r == c ? 1.5f : 0.0f) - 0.5f * a);
}

// ---------------- NS matmul: C = A*B (B symmetric -> NT). MODE1: C = 1.5I - 0.5*A*B ----------------
template <int MODE>
__global__ __launch_bounds__(256)
void k_ns(const unsigned short* __restrict__ A0, const unsigned short* __restrict__ B0,
          unsigned short* __restrict__ C0,
          const unsigned short* __restrict__ A1, const unsigned short* __restrict__ B1,
          unsigned short* __restrict__ C1) {
  const unsigned short* A  = blockIdx.y ? A1 : A0;
  const unsigned short* Bm = blockIdx.y ? B1 : B0;
  unsigned short* Cm       = blockIdx.y ? C1 : C0;
  int bid = blockIdx.x;
  int tile = bid & 15, b = bid >> 4;
  int tm = tile >> 2, tn = tile & 3;

  __shared__ __align__(16) unsigned short As[64 * 64];
  __shared__ __align__(16) unsigned short Bs[64 * 64];

  int tid = threadIdx.x, lane = tid & 63, w = tid >> 6;
  int wm = w >> 1, wn = w & 1;
  int fr = lane & 15, kg = lane >> 4;

  int col8 = ((tid & 7) ^ ((tid >> 3) & 7)) * 8;
  const unsigned short* ab = A  + (size_t)b * ND * ND + (size_t)(tm * 64 + (tid >> 3)) * ND + col8;
  const unsigned short* bb = Bm + (size_t)b * ND * ND + (size_t)(tn * 64 + (tid >> 3)) * ND + col8;
  char* AsB = (char*)As + (size_t)w * 1024;
  char* BsB = (char*)Bs + (size_t)w * 1024;
  const char* Asc = (const char*)As;
  const char* Bsc = (const char*)Bs;

  f32x4 acc[2][2];
#pragma unroll
  for (int i = 0; i < 2; ++i)
#pragma unroll
    for (int j = 0; j < 2; ++j) acc[i][j] = f32x4{0.f, 0.f, 0.f, 0.f};

  for (int kt = 0; kt < 4; ++kt) {
#pragma unroll
    for (int r = 0; r < 2; ++r) {
      GLD16(ab + (size_t)r * 32 * ND + kt * 64, AsB + r * 4096);
      GLD16(bb + (size_t)r * 32 * ND + kt * 64, BsB + r * 4096);
    }
    __syncthreads();
#pragma unroll
    for (int kk = 0; kk < 2; ++kk) {
      bf16x8 av[2], bv[2];
      int swz = (fr & 7) << 4;
#pragma unroll
      for (int fm = 0; fm < 2; ++fm)
        av[fm] = *(const bf16x8*)(Asc + (wm * 32 + fm * 16 + fr) * 128 + ((kk * 64 + kg * 16) ^ swz));
#pragma unroll
      for (int fn = 0; fn < 2; ++fn)
        bv[fn] = *(const bf16x8*)(Bsc + (wn * 32 + fn * 16 + fr) * 128 + ((kk * 64 + kg * 16) ^ swz));
#pragma unroll
      for (int fm = 0; fm < 2; ++fm)
#pragma unroll
        for (int fn = 0; fn < 2; ++fn)
          acc[fm][fn] = __builtin_amdgcn_mfma_f32_16x16x32_bf16(av[fm], bv[fn], acc[fm][fn], 0, 0, 0);
    }
    __syncthreads();
  }

  unsigned short* Cb = Cm + (size_t)b * ND * ND;
#pragma unroll
  for (int fm = 0; fm < 2; ++fm)
#pragma unroll
    for (int fn = 0; fn < 2; ++fn)
#pragma unroll
      for (int ri = 0; ri < 4; ++ri) {
        int row = tm * 64 + wm * 32 + fm * 16 + kg * 4 + ri;
        int col = tn * 64 + wn * 32 + fn * 16 + fr;
        float v = acc[fm][fn][ri];
        if (MODE == 1) v = (row == col ? 1.5f : 0.0f) - 0.5f * v;
        Cb[row * ND + col] = f2bf(v);
      }
}

// ---------------- final: out = triuvec(Y @ ZY) * sqrt(normA) ----------------
__global__ __launch_bounds__(256)
void k_final(const unsigned short* __restrict__ Y, const unsigned short* __restrict__ ZY,
             const float* __restrict__ nrm, float* __restrict__ out) {
  const int tmv[10] = {0, 1, 2, 3, 5, 6, 7, 10, 11, 15};  // upper-tri 64x64 tiles
  int bid = blockIdx.x;
  int t = bid % 10, b = bid / 10;
  int tile = tmv[t];
  int tm = tile >> 2, tn = tile & 3;

  __shared__ __align__(16) unsigned short As[64 * 64];
  __shared__ __align__(16) unsigned short Bs[64 * 64];

  int tid = threadIdx.x, lane = tid & 63, w = tid >> 6;
  int wm = w >> 1, wn = w & 1;
  int fr = lane & 15, kg = lane >> 4;

  int col8 = ((tid & 7) ^ ((tid >> 3) & 7)) * 8;
  const unsigned short* ab = Y  + (size_t)b * ND * ND + (size_t)(tm * 64 + (tid >> 3)) * ND + col8;
  const unsigned short* bb = ZY + (size_t)b * ND * ND + (size_t)(tn * 64 + (tid >> 3)) * ND + col8;
  char* AsB = (char*)As + (size_t)w * 1024;
  char* BsB = (char*)Bs + (size_t)w * 1024;
  const char* Asc = (const char*)As;
  const char* Bsc = (const char*)Bs;

  f32x4 acc[2][2];
#pragma unroll
  for (int i = 0; i < 2; ++i)
#pragma unroll
    for (int j = 0; j < 2; ++j) acc[i][j] = f32x4{0.f, 0.f, 0.f, 0.f};

  for (int kt = 0; kt < 4; ++kt) {
#pragma unroll
    for (int r = 0; r < 2; ++r) {
      GLD16(ab + (size_t)r * 32 * ND + kt * 64, AsB + r * 4096);
      GLD16(bb + (size_t)r * 32 * ND + kt * 64, BsB + r * 4096);
    }
    __syncthreads();
#pragma unroll
    for (int kk = 0; kk < 2; ++kk) {
      bf16x8 av[2], bv[2];
      int swz = (fr & 7) << 4;
#pragma unroll
      for (int fm = 0; fm < 2; ++fm)
        av[fm] = *(const bf16x8*)(Asc + (wm * 32 + fm * 16 + fr) * 128 + ((kk * 64 + kg * 16) ^ swz));
#pragma unroll
      for (int fn = 0; fn < 2; ++fn)
        bv[fn] = *(const bf16x8*)(Bsc + (wn * 32 + fn * 16 + fr) * 128 + ((kk * 64 + kg * 16) ^ swz));
#pragma unroll
      for (int fm = 0; fm < 2; ++fm)
#pragma unroll
        for (int fn = 0; fn < 2; ++fn)
          acc[fm][fn] = __builtin_amdgcn_mfma_f32_16x16x32_bf16(av[fm], bv[fn], acc[fm][fn], 0, 0, 0);
    }
    __syncthreads();
  }

  float sc = sqrtf(nrm[b]);
#pragma unroll
  for (int fm = 0; fm < 2; ++fm)
#pragma unroll
    for (int fn = 0; fn < 2; ++fn)
#pragma unroll
      for (int ri = 0; ri < 4; ++ri) {
        int row = tm * 64 + wm * 32 + fm * 16 + kg * 4 + ri;
        int col = tn * 64 + wn * 32 + fn * 16 + fr;
        if (row <= col) {
          int idx = row * ND - (row * (row - 1)) / 2 + (col - row);
          out[(size_t)b * NTRI + idx] = acc[fm][fn][ri] * sc;
        }
      }
}

extern "C" void kernel_launch(void* const* d_in, const int* in_sizes, int n_in,
                              void* d_out, int out_size, void* d_ws, size_t ws_size,
                              hipStream_t stream) {
  const float* x   = (const float*)d_in[0];
  const float* raw = (const float*)d_in[1];
  float* out = (float*)d_out;
  char* ws = (char*)d_ws;

  const size_t Z_OFF   = 0;
  const size_t S_OFF   = Z_OFF + (size_t)NB * NC * NM * 2;            // 102,760,448
  const size_t P_OFF   = S_OFF + (size_t)NB * NC * 4;                 // + 16,384
  const size_t COV_OFF = P_OFF + (size_t)SPLITK * NB * 3 * 16384 * 4; // + 50,331,648
  const size_t NA_OFF  = COV_OFF + (size_t)NB * ND * ND * 4;          // + 4,194,304
  const size_t AN_OFF  = NA_OFF + 64;
  const size_t MATB    = (size_t)NB * ND * ND * 2;                    // 2,097,152
  const size_t Y_OFF   = AN_OFF + MATB;
  const size_t ZM_OFF  = Y_OFF + MATB;
  const size_t ZY_OFF  = ZM_OFF + MATB;
  const size_t Y2_OFF  = ZY_OFF + MATB;
  const size_t Z2_OFF  = Y2_OFF + MATB;

  unsigned short* z   = (unsigned short*)(ws + Z_OFF);
  float* ssum = (float*)(ws + S_OFF);
  float* P    = (float*)(ws + P_OFF);
  float* cov  = (float*)(ws + COV_OFF);
  float* nrm  = (float*)(ws + NA_OFF);
  unsigned short* An  = (unsigned short*)(ws + AN_OFF);
  unsigned short* Yb  = (unsigned short*)(ws + Y_OFF);
  unsigned short* Zb  = (unsigned short*)(ws + ZM_OFF);
  unsigned short* ZYb = (unsigned short*)(ws + ZY_OFF);
  unsigned short* Y2b = (unsigned short*)(ws + Y2_OFF);
  unsigned short* Z2b = (unsigned short*)(ws + Z2_OFF);

  hipMemsetAsync(nrm, 0, 64, stream);
  k_z<<<NB * NC, 256, 0, stream>>>(x, raw, z, ssum, out + ATT_OUT_OFF);
  k_cov<<<NB * 3 * SPLITK, 256, 0, stream>>>(z, P);
  k_asm<<<NB * ND * ND / 256, 256, 0, stream>>>(P, ssum, cov, nrm);
  k_anzy<<<NB * ND * ND / 256, 256, 0, stream>>>(cov, nrm, An, Zb);

  // Y1 = An @ ZY0   (ZY0 stored in Zb)
  k_ns<0><<<dim3(256, 1), 256, 0, stream>>>(An, Zb, Yb, An, Zb, Yb);

  unsigned short *Yc = Yb, *Zc = Zb, *Yn = Y2b, *Zn = Z2b;
  for (int it = 0; it < 3; ++it) {
    k_ns<1><<<dim3(256, 1), 256, 0, stream>>>(Zc, Yc, ZYb, Zc, Yc, ZYb);      // ZY = 1.5I - 0.5 Z@Y
    k_ns<0><<<dim3(256, 2), 256, 0, stream>>>(Yc, ZYb, Yn, ZYb, Zc, Zn);      // Y'=Y@ZY ; Z'=ZY@Z
    unsigned short* t;
    t = Yc; Yc = Yn; Yn = t;
    t = Zc; Zc = Zn; Zn = t;
  }
  k_ns<1><<<dim3(256, 1), 256, 0, stream>>>(Zc, Yc, ZYb, Zc, Yc, ZYb);        // final ZY
  k_final<<<160, 256, 0, stream>>>(Yc, ZYb, nrm, out);                        // triuvec(Y@ZY)*sqrt(normA)
}

// Round 3
// 241.054 us; speedup vs baseline: 1.0396x; 1.0396x over previous
//
#include <hip/hip_runtime.h>

#define NB 16
#define NC 256
#define NHW 784
#define NATN 16
#define NM 12544          // 16*784
#define ND 256
#define NTRI 32896        // 256*257/2
#define ATT_OUT_OFF 526336
#define SPLITK 16

typedef float f32x4 __attribute__((ext_vector_type(4)));
typedef short bf16x8 __attribute__((ext_vector_type(8)));

static __device__ __forceinline__ unsigned short f2bf(float f) {
  unsigned int u = __float_as_uint(f);
  u = (u + 0x7FFFu + ((u >> 16) & 1u)) >> 16;   // RNE
  return (unsigned short)u;
}

#define GLD16(g, l) __builtin_amdgcn_global_load_lds(                      \
    (const __attribute__((address_space(1))) void*)(g),                    \
    (__attribute__((address_space(3))) void*)(l), 16, 0, 0)

// ---------------- z = (sigmoid(raw)+eps) * x  (bf16) + row sums; c==0 blocks emit att ----------------
__global__ __launch_bounds__(256)
void k_z(const float* __restrict__ x, const float* __restrict__ raw,
         unsigned short* __restrict__ z, float* __restrict__ s,
         float* __restrict__ out_att) {
  int bc = blockIdx.x;                 // b*256 + c
  int b  = bc >> 8;
  int c  = bc & 255;
  int t  = threadIdx.x;
  const float* xr = x + (size_t)bc * NHW;
  unsigned short* zr = z + (size_t)bc * NM;
  float sum = 0.f;
  if (t < 196) {
    float4 xv = ((const float4*)xr)[t];
    for (int a = 0; a < NATN; ++a) {
      const float* rr = raw + (size_t)(b * NATN + a) * NHW;
      float4 rv = ((const float4*)rr)[t];
      float a0 = 1.0f / (1.0f + __expf(-rv.x)) + 1e-12f;
      float a1 = 1.0f / (1.0f + __expf(-rv.y)) + 1e-12f;
      float a2 = 1.0f / (1.0f + __expf(-rv.z)) + 1e-12f;
      float a3 = 1.0f / (1.0f + __expf(-rv.w)) + 1e-12f;
      float v0 = a0 * xv.x, v1 = a1 * xv.y, v2 = a2 * xv.z, v3 = a3 * xv.w;
      ushort4 zv;
      zv.x = f2bf(v0); zv.y = f2bf(v1); zv.z = f2bf(v2); zv.w = f2bf(v3);
      *(ushort4*)&zr[a * NHW + t * 4] = zv;
      sum += v0 + v1 + v2 + v3;
      if (c == 0) {
        float4 av = make_float4(a0, a1, a2, a3);
        *(float4*)&out_att[(size_t)(b * NATN + a) * NHW + t * 4] = av;
      }
    }
  }
  for (int off = 32; off; off >>= 1) sum += __shfl_down(sum, off, 64);
  __shared__ float red[4];
  if ((t & 63) == 0) red[t >> 6] = sum;
  __syncthreads();
  if (t == 0) s[bc] = red[0] + red[1] + red[2] + red[3];
}

// ---------------- cov GEMM: P[split][b][t3] += z_tile * z_tile^T ----------------
__global__ __launch_bounds__(256)
void k_cov(const unsigned short* __restrict__ z, float* __restrict__ P) {
  int bid = blockIdx.x;
  int split = bid & 15;
  int t3 = (bid >> 4) % 3;
  int b = bid / 48;
  int tm = (t3 == 2) ? 1 : 0;
  int tn = (t3 >= 1) ? 1 : 0;

  __shared__ __align__(16) unsigned short As[128 * 64];
  __shared__ __align__(16) unsigned short Bs[128 * 64];

  int tid = threadIdx.x;
  int lane = tid & 63, w = tid >> 6;
  int wm = w >> 1, wn = w & 1;
  int fr = lane & 15, kg = lane >> 4;

  const unsigned short* zb = z + (size_t)b * NC * NM;
  int col8 = ((tid & 7) ^ ((tid >> 3) & 7)) * 8;       // source pre-swizzle
  const unsigned short* ab = zb + (size_t)(tm * 128 + (tid >> 3)) * NM + col8;
  const unsigned short* bb = zb + (size_t)(tn * 128 + (tid >> 3)) * NM + col8;

  f32x4 acc[4][4];
#pragma unroll
  for (int i = 0; i < 4; ++i)
#pragma unroll
    for (int j = 0; j < 4; ++j) acc[i][j] = f32x4{0.f, 0.f, 0.f, 0.f};

  int ktiles = 12 + (split < 4 ? 1 : 0);
  int k0 = (split * 12 + (split < 4 ? split : 4)) * 64;
  char* AsB = (char*)As + (size_t)w * 1024;
  char* BsB = (char*)Bs + (size_t)w * 1024;
  const char* Asc = (const char*)As;
  const char* Bsc = (const char*)Bs;

  for (int kt = 0; kt < ktiles; ++kt) {
    int kb = k0 + kt * 64;
#pragma unroll
    for (int r = 0; r < 4; ++r) GLD16(ab + (size_t)r * 32 * NM + kb, AsB + r * 4096);
#pragma unroll
    for (int r = 0; r < 4; ++r) GLD16(bb + (size_t)r * 32 * NM + kb, BsB + r * 4096);
    __syncthreads();
#pragma unroll
    for (int kk = 0; kk < 2; ++kk) {
      bf16x8 av[4], bv[4];
      int swz = (fr & 7) << 4;
#pragma unroll
      for (int fm = 0; fm < 4; ++fm)
        av[fm] = *(const bf16x8*)(Asc + (wm * 64 + fm * 16 + fr) * 128 + ((kk * 64 + kg * 16) ^ swz));
#pragma unroll
      for (int fn = 0; fn < 4; ++fn)
        bv[fn] = *(const bf16x8*)(Bsc + (wn * 64 + fn * 16 + fr) * 128 + ((kk * 64 + kg * 16) ^ swz));
#pragma unroll
      for (int fm = 0; fm < 4; ++fm)
#pragma unroll
        for (int fn = 0; fn < 4; ++fn)
          acc[fm][fn] = __builtin_amdgcn_mfma_f32_16x16x32_bf16(av[fm], bv[fn], acc[fm][fn], 0, 0, 0);
    }
    __syncthreads();
  }

  float* Pb = P + ((size_t)(split * NB + b) * 3 + t3) * 16384;
#pragma unroll
  for (int fm = 0; fm < 4; ++fm)
#pragma unroll
    for (int fn = 0; fn < 4; ++fn)
#pragma unroll
      for (int ri = 0; ri < 4; ++ri) {
        int row = wm * 64 + fm * 16 + kg * 4 + ri;   // tile-local
        int col = wn * 64 + fn * 16 + fr;
        Pb[row * 128 + col] = acc[fm][fn][ri];
      }
}

// ---------------- cov = (sum P)/M - s s^T / M^2 ; fully coalesced over stored tiles ----------------
// grid: b*192 + t3*64 + blk  (each (b,t3) tile = 64 blocks x 256 thr = 16384 elems)
__global__ __launch_bounds__(256)
void k_asm(const float* __restrict__ P, const float* __restrict__ s,
           float* __restrict__ cov, float* __restrict__ nrm) {
  int gid = blockIdx.x;
  int b = gid / 192;
  int rem = gid - b * 192;
  int t3 = rem >> 6;
  int loc = (rem & 63) * 256 + threadIdx.x;
  int row = loc >> 7, col = loc & 127;
  int tm = (t3 == 2) ? 1 : 0;
  int tn = (t3 >= 1) ? 1 : 0;
  int r = tm * 128 + row, c = tn * 128 + col;
  const float invM = 1.0f / 12544.0f;
  float g = 0.f;
#pragma unroll
  for (int sp = 0; sp < SPLITK; ++sp)
    g += P[((size_t)(sp * NB + b) * 3 + t3) * 16384 + loc];
  float v = g * invM - s[b * NC + r] * s[b * NC + c] * (invM * invM);
  cov[(size_t)b * 65536 + r * 256 + c] = v;
  if (t3 == 1) cov[(size_t)b * 65536 + c * 256 + r] = v;   // quadrant (1,0)
  if (r == c) atomicAdd(&nrm[b], v);
}

// ---------------- An = cov/normA (bf16); Z0 = 1.5I - 0.5 An (bf16) ----------------
__global__ void k_anzy(const float* __restrict__ cov, const float* __restrict__ nrm,
                       unsigned short* __restrict__ An, unsigned short* __restrict__ Z) {
  int i = blockIdx.x * 256 + threadIdx.x;
  int b = i >> 16;
  int rc = i & 65535;
  int r = rc >> 8, c = rc & 255;
  float a = cov[i] / nrm[b];
  An[i] = f2bf(a);
  Z[i]  = f2bf((r == c ? 1.5f : 0.0f) - 0.5f * a);
}

// ---------------- NS matmul, single-stage K=256: C = A*B (B sym -> NT). MODE1: 1.5I-0.5AB ----------------
// LDS holds full 64x256 panels; one barrier; 8 MFMA k-steps.
template <int MODE>
__global__ __launch_bounds__(256)
void k_ns(const unsigned short* __restrict__ A0, const unsigned short* __restrict__ B0,
          unsigned short* __restrict__ C0,
          const unsigned short* __restrict__ A1, const unsigned short* __restrict__ B1,
          unsigned short* __restrict__ C1) {
  const unsigned short* A  = blockIdx.y ? A1 : A0;
  const unsigned short* Bm = blockIdx.y ? B1 : B0;
  unsigned short* Cm       = blockIdx.y ? C1 : C0;
  int bid = blockIdx.x;
  int tile = bid & 15, b = bid >> 4;
  int tm = tile >> 2, tn = tile & 3;

  __shared__ __align__(16) unsigned short As[64 * 256];
  __shared__ __align__(16) unsigned short Bs[64 * 256];

  int tid = threadIdx.x, lane = tid & 63, w = tid >> 6;
  int wm = w >> 1, wn = w & 1;
  int fr = lane & 15, kg = lane >> 4;

  // staging: thread t, iter j -> global row (t>>5)+j*8, chunk (t&31)^(t>>5)
  const unsigned short* Ab = A  + (size_t)b * 65536 + (size_t)(tm * 64) * 256;
  const unsigned short* Bb = Bm + (size_t)b * 65536 + (size_t)(tn * 64) * 256;
  int r8 = tid >> 5;                       // 0..7
  size_t srcoff = (size_t)r8 * 256 + (size_t)((tid & 31) ^ r8) * 8;
  char* AsW = (char*)As + (size_t)(w * 2) * 512;
  char* BsW = (char*)Bs + (size_t)(w * 2) * 512;
#pragma unroll
  for (int j = 0; j < 8; ++j) {
    GLD16(Ab + srcoff + (size_t)j * 8 * 256, AsW + (size_t)j * 8 * 512);
    GLD16(Bb + srcoff + (size_t)j * 8 * 256, BsW + (size_t)j * 8 * 512);
  }
  __syncthreads();

  const char* Asc = (const char*)As;
  const char* Bsc = (const char*)Bs;
  f32x4 acc[2][2];
#pragma unroll
  for (int i = 0; i < 2; ++i)
#pragma unroll
    for (int j = 0; j < 2; ++j) acc[i][j] = f32x4{0.f, 0.f, 0.f, 0.f};

  int f7 = fr & 7;
#pragma unroll
  for (int kk = 0; kk < 8; ++kk) {
    bf16x8 av[2], bv[2];
#pragma unroll
    for (int fm = 0; fm < 2; ++fm) {
      int row = wm * 32 + fm * 16 + fr;
      av[fm] = *(const bf16x8*)(Asc + row * 512 + ((((kk << 2) | kg) ^ f7) << 4));
    }
#pragma unroll
    for (int fn = 0; fn < 2; ++fn) {
      int row = wn * 32 + fn * 16 + fr;
      bv[fn] = *(const bf16x8*)(Bsc + row * 512 + ((((kk << 2) | kg) ^ f7) << 4));
    }
#pragma unroll
    for (int fm = 0; fm < 2; ++fm)
#pragma unroll
      for (int fn = 0; fn < 2; ++fn)
        acc[fm][fn] = __builtin_amdgcn_mfma_f32_16x16x32_bf16(av[fm], bv[fn], acc[fm][fn], 0, 0, 0);
  }

  unsigned short* Cb = Cm + (size_t)b * ND * ND;
#pragma unroll
  for (int fm = 0; fm < 2; ++fm)
#pragma unroll
    for (int fn = 0; fn < 2; ++fn)
#pragma unroll
      for (int ri = 0; ri < 4; ++ri) {
        int row = tm * 64 + wm * 32 + fm * 16 + kg * 4 + ri;
        int col = tn * 64 + wn * 32 + fn * 16 + fr;
        float v = acc[fm][fn][ri];
        if (MODE == 1) v = (row == col ? 1.5f : 0.0f) - 0.5f * v;
        Cb[row * ND + col] = f2bf(v);
      }
}

// ---------------- final: out = triuvec(Y @ ZY) * sqrt(normA), single-stage K=256 ----------------
__global__ __launch_bounds__(256)
void k_final(const unsigned short* __restrict__ Y, const unsigned short* __restrict__ ZY,
             const float* __restrict__ nrm, float* __restrict__ out) {
  const int tmv[10] = {0, 1, 2, 3, 5, 6, 7, 10, 11, 15};  // upper-tri 64x64 tiles
  int bid = blockIdx.x;
  int t = bid % 10, b = bid / 10;
  int tile = tmv[t];
  int tm = tile >> 2, tn = tile & 3;

  __shared__ __align__(16) unsigned short As[64 * 256];
  __shared__ __align__(16) unsigned short Bs[64 * 256];

  int tid = threadIdx.x, lane = tid & 63, w = tid >> 6;
  int wm = w >> 1, wn = w & 1;
  int fr = lane & 15, kg = lane >> 4;

  const unsigned short* Ab = Y  + (size_t)b * 65536 + (size_t)(tm * 64) * 256;
  const unsigned short* Bb = ZY + (size_t)b * 65536 + (size_t)(tn * 64) * 256;
  int r8 = tid >> 5;
  size_t srcoff = (size_t)r8 * 256 + (size_t)((tid & 31) ^ r8) * 8;
  char* AsW = (char*)As + (size_t)(w * 2) * 512;
  char* BsW = (char*)Bs + (size_t)(w * 2) * 512;
#pragma unroll
  for (int j = 0; j < 8; ++j) {
    GLD16(Ab + srcoff + (size_t)j * 8 * 256, AsW + (size_t)j * 8 * 512);
    GLD16(Bb + srcoff + (size_t)j * 8 * 256, BsW + (size_t)j * 8 * 512);
  }
  __syncthreads();

  const char* Asc = (const char*)As;
  const char* Bsc = (const char*)Bs;
  f32x4 acc[2][2];
#pragma unroll
  for (int i = 0; i < 2; ++i)
#pragma unroll
    for (int j = 0; j < 2; ++j) acc[i][j] = f32x4{0.f, 0.f, 0.f, 0.f};

  int f7 = fr & 7;
#pragma unroll
  for (int kk = 0; kk < 8; ++kk) {
    bf16x8 av[2], bv[2];
#pragma unroll
    for (int fm = 0; fm < 2; ++fm) {
      int row = wm * 32 + fm * 16 + fr;
      av[fm] = *(const bf16x8*)(Asc + row * 512 + ((((kk << 2) | kg) ^ f7) << 4));
    }
#pragma unroll
    for (int fn = 0; fn < 2; ++fn) {
      int row = wn * 32 + fn * 16 + fr;
      bv[fn] = *(const bf16x8*)(Bsc + row * 512 + ((((kk << 2) | kg) ^ f7) << 4));
    }
#pragma unroll
    for (int fm = 0; fm < 2; ++fm)
#pragma unroll
      for (int fn = 0; fn < 2; ++fn)
        acc[fm][fn] = __builtin_amdgcn_mfma_f32_16x16x32_bf16(av[fm], bv[fn], acc[fm][fn], 0, 0, 0);
  }

  float sc = sqrtf(nrm[b]);
#pragma unroll
  for (int fm = 0; fm < 2; ++fm)
#pragma unroll
    for (int fn = 0; fn < 2; ++fn)
#pragma unroll
      for (int ri = 0; ri < 4; ++ri) {
        int row = tm * 64 + wm * 32 + fm * 16 + kg * 4 + ri;
        int col = tn * 64 + wn * 32 + fn * 16 + fr;
        if (row <= col) {
          int idx = row * ND - (row * (row - 1)) / 2 + (col - row);
          out[(size_t)b * NTRI + idx] = acc[fm][fn][ri] * sc;
        }
      }
}

extern "C" void kernel_launch(void* const* d_in, const int* in_sizes, int n_in,
                              void* d_out, int out_size, void* d_ws, size_t ws_size,
                              hipStream_t stream) {
  const float* x   = (const float*)d_in[0];
  const float* raw = (const float*)d_in[1];
  float* out = (float*)d_out;
  char* ws = (char*)d_ws;

  const size_t Z_OFF   = 0;
  const size_t S_OFF   = Z_OFF + (size_t)NB * NC * NM * 2;            // 102,760,448
  const size_t P_OFF   = S_OFF + (size_t)NB * NC * 4;                 // + 16,384
  const size_t COV_OFF = P_OFF + (size_t)SPLITK * NB * 3 * 16384 * 4; // + 50,331,648
  const size_t NA_OFF  = COV_OFF + (size_t)NB * ND * ND * 4;          // + 4,194,304
  const size_t AN_OFF  = NA_OFF + 64;
  const size_t MATB    = (size_t)NB * ND * ND * 2;                    // 2,097,152
  const size_t Y_OFF   = AN_OFF + MATB;
  const size_t ZM_OFF  = Y_OFF + MATB;
  const size_t ZY_OFF  = ZM_OFF + MATB;
  const size_t Y2_OFF  = ZY_OFF + MATB;
  const size_t Z2_OFF  = Y2_OFF + MATB;

  unsigned short* z   = (unsigned short*)(ws + Z_OFF);
  float* ssum = (float*)(ws + S_OFF);
  float* P    = (float*)(ws + P_OFF);
  float* cov  = (float*)(ws + COV_OFF);
  float* nrm  = (float*)(ws + NA_OFF);
  unsigned short* An  = (unsigned short*)(ws + AN_OFF);
  unsigned short* Yb  = (unsigned short*)(ws + Y_OFF);
  unsigned short* Zb  = (unsigned short*)(ws + ZM_OFF);
  unsigned short* ZYb = (unsigned short*)(ws + ZY_OFF);
  unsigned short* Y2b = (unsigned short*)(ws + Y2_OFF);
  unsigned short* Z2b = (unsigned short*)(ws + Z2_OFF);

  hipMemsetAsync(nrm, 0, 64, stream);
  k_z<<<NB * NC, 256, 0, stream>>>(x, raw, z, ssum, out + ATT_OUT_OFF);
  k_cov<<<NB * 3 * SPLITK, 256, 0, stream>>>(z, P);
  k_asm<<<NB * 3 * 64, 256, 0, stream>>>(P, ssum, cov, nrm);
  k_anzy<<<NB * ND * ND / 256, 256, 0, stream>>>(cov, nrm, An, Zb);

  // Y1 = An @ ZY0   (ZY0 stored in Zb)
  k_ns<0><<<dim3(256, 1), 256, 0, stream>>>(An, Zb, Yb, An, Zb, Yb);

  unsigned short *Yc = Yb, *Zc = Zb, *Yn = Y2b, *Zn = Z2b;
  for (int it = 0; it < 3; ++it) {
    k_ns<1><<<dim3(256, 1), 256, 0, stream>>>(Zc, Yc, ZYb, Zc, Yc, ZYb);      // ZY = 1.5I - 0.5 Z@Y
    k_ns<0><<<dim3(256, 2), 256, 0, stream>>>(Yc, ZYb, Yn, ZYb, Zc, Zn);      // Y'=Y@ZY ; Z'=ZY@Z
    unsigned short* t;
    t = Yc; Yc = Yn; Yn = t;
    t = Zc; Zc = Zn; Zn = t;
  }
  k_ns<1><<<dim3(256, 1), 256, 0, stream>>>(Zc, Yc, ZYb, Zc, Yc, ZYb);        // final ZY
  k_final<<<160, 256, 0, stream>>>(Yc, ZYb, nrm, out);                        // triuvec(Y@ZY)*sqrt(normA)
}

// Round 12
// 198.629 us; speedup vs baseline: 1.2616x; 1.2136x over previous
//
#include <hip/hip_runtime.h>

#define NB 16
#define NC 256
#define NHW 784
#define NATN 16
#define NM 12544          // 16*784
#define ND 256
#define NTRI 32896        // 256*257/2
#define ATT_OUT_OFF 526336
#define SPLITK 16

typedef float f32x4 __attribute__((ext_vector_type(4)));
typedef short bf16x8 __attribute__((ext_vector_type(8)));

static __device__ __forceinline__ unsigned short f2bf(float f) {
  unsigned int u = __float_as_uint(f);
  u = (u + 0x7FFFu + ((u >> 16) & 1u)) >> 16;   // RNE
  return (unsigned short)u;
}

#define GLD16(g, l) __builtin_amdgcn_global_load_lds(                      \
    (const __attribute__((address_space(1))) void*)(g),                    \
    (__attribute__((address_space(3))) void*)(l), 16, 0, 0)

// ---------------- z = (sigmoid(raw)+eps) * x  (bf16) + row sums; c==0 blocks emit att ----------------
__global__ __launch_bounds__(256)
void k_z(const float* __restrict__ x, const float* __restrict__ raw,
         unsigned short* __restrict__ z, float* __restrict__ s,
         float* __restrict__ out_att) {
  int bc = blockIdx.x;                 // b*256 + c
  int b  = bc >> 8;
  int c  = bc & 255;
  int t  = threadIdx.x;
  const float* xr = x + (size_t)bc * NHW;
  unsigned short* zr = z + (size_t)bc * NM;
  float sum = 0.f;
  if (t < 196) {
    float4 xv = ((const float4*)xr)[t];
    for (int a = 0; a < NATN; ++a) {
      const float* rr = raw + (size_t)(b * NATN + a) * NHW;
      float4 rv = ((const float4*)rr)[t];
      float a0 = 1.0f / (1.0f + __expf(-rv.x)) + 1e-12f;
      float a1 = 1.0f / (1.0f + __expf(-rv.y)) + 1e-12f;
      float a2 = 1.0f / (1.0f + __expf(-rv.z)) + 1e-12f;
      float a3 = 1.0f / (1.0f + __expf(-rv.w)) + 1e-12f;
      float v0 = a0 * xv.x, v1 = a1 * xv.y, v2 = a2 * xv.z, v3 = a3 * xv.w;
      ushort4 zv;
      zv.x = f2bf(v0); zv.y = f2bf(v1); zv.z = f2bf(v2); zv.w = f2bf(v3);
      *(ushort4*)&zr[a * NHW + t * 4] = zv;
      sum += v0 + v1 + v2 + v3;
      if (c == 0) {
        float4 av = make_float4(a0, a1, a2, a3);
        *(float4*)&out_att[(size_t)(b * NATN + a) * NHW + t * 4] = av;
      }
    }
  }
  for (int off = 32; off; off >>= 1) sum += __shfl_down(sum, off, 64);
  __shared__ float red[4];
  if ((t & 63) == 0) red[t >> 6] = sum;
  __syncthreads();
  if (t == 0) s[bc] = red[0] + red[1] + red[2] + red[3];
}

// ---------------- cov GEMM: P[split][b][t3] += z_tile * z_tile^T ----------------
__global__ __launch_bounds__(256)
void k_cov(const unsigned short* __restrict__ z, float* __restrict__ P) {
  int bid = blockIdx.x;
  int split = bid & 15;
  int t3 = (bid >> 4) % 3;
  int b = bid / 48;
  int tm = (t3 == 2) ? 1 : 0;
  int tn = (t3 >= 1) ? 1 : 0;

  __shared__ __align__(16) unsigned short As[128 * 64];
  __shared__ __align__(16) unsigned short Bs[128 * 64];

  int tid = threadIdx.x;
  int lane = tid & 63, w = tid >> 6;
  int wm = w >> 1, wn = w & 1;
  int fr = lane & 15, kg = lane >> 4;

  const unsigned short* zb = z + (size_t)b * NC * NM;
  int col8 = ((tid & 7) ^ ((tid >> 3) & 7)) * 8;       // source pre-swizzle
  const unsigned short* ab = zb + (size_t)(tm * 128 + (tid >> 3)) * NM + col8;
  const unsigned short* bb = zb + (size_t)(tn * 128 + (tid >> 3)) * NM + col8;

  f32x4 acc[4][4];
#pragma unroll
  for (int i = 0; i < 4; ++i)
#pragma unroll
    for (int j = 0; j < 4; ++j) acc[i][j] = f32x4{0.f, 0.f, 0.f, 0.f};

  int ktiles = 12 + (split < 4 ? 1 : 0);
  int k0 = (split * 12 + (split < 4 ? split : 4)) * 64;
  char* AsB = (char*)As + (size_t)w * 1024;
  char* BsB = (char*)Bs + (size_t)w * 1024;
  const char* Asc = (const char*)As;
  const char* Bsc = (const char*)Bs;

  for (int kt = 0; kt < ktiles; ++kt) {
    int kb = k0 + kt * 64;
#pragma unroll
    for (int r = 0; r < 4; ++r) GLD16(ab + (size_t)r * 32 * NM + kb, AsB + r * 4096);
#pragma unroll
    for (int r = 0; r < 4; ++r) GLD16(bb + (size_t)r * 32 * NM + kb, BsB + r * 4096);
    __syncthreads();
#pragma unroll
    for (int kk = 0; kk < 2; ++kk) {
      bf16x8 av[4], bv[4];
      int swz = (fr & 7) << 4;
#pragma unroll
      for (int fm = 0; fm < 4; ++fm)
        av[fm] = *(const bf16x8*)(Asc + (wm * 64 + fm * 16 + fr) * 128 + ((kk * 64 + kg * 16) ^ swz));
#pragma unroll
      for (int fn = 0; fn < 4; ++fn)
        bv[fn] = *(const bf16x8*)(Bsc + (wn * 64 + fn * 16 + fr) * 128 + ((kk * 64 + kg * 16) ^ swz));
#pragma unroll
      for (int fm = 0; fm < 4; ++fm)
#pragma unroll
        for (int fn = 0; fn < 4; ++fn)
          acc[fm][fn] = __builtin_amdgcn_mfma_f32_16x16x32_bf16(av[fm], bv[fn], acc[fm][fn], 0, 0, 0);
    }
    __syncthreads();
  }

  float* Pb = P + ((size_t)(split * NB + b) * 3 + t3) * 16384;
#pragma unroll
  for (int fm = 0; fm < 4; ++fm)
#pragma unroll
    for (int fn = 0; fn < 4; ++fn)
#pragma unroll
      for (int ri = 0; ri < 4; ++ri) {
        int row = wm * 64 + fm * 16 + kg * 4 + ri;   // tile-local
        int col = wn * 64 + fn * 16 + fr;
        Pb[row * 128 + col] = acc[fm][fn][ri];
      }
}

// ---------------- trace: nrm[b] = sum_d [ (sum_sp Pdiag)/M - s_d^2/M^2 ]  (no atomics) ----------------
__global__ __launch_bounds__(256)
void k_trace(const float* __restrict__ P, const float* __restrict__ s,
             float* __restrict__ nrm) {
  int b = blockIdx.x, t = threadIdx.x;
  int t3 = (t < 128) ? 0 : 2;
  int loc = (t & 127) * 129;
  const float invM = 1.0f / 12544.0f;
  float g = 0.f;
#pragma unroll
  for (int sp = 0; sp < SPLITK; ++sp)
    g += P[((size_t)(sp * NB + b) * 3 + t3) * 16384 + loc];
  float sd = s[b * NC + t];
  float v = g * invM - sd * sd * (invM * invM);
  for (int off = 32; off; off >>= 1) v += __shfl_down(v, off, 64);
  __shared__ float red[4];
  if ((t & 63) == 0) red[t >> 6] = v;
  __syncthreads();
  if (t == 0) nrm[b] = red[0] + red[1] + red[2] + red[3];
}

// ---------------- cov = (sum P)/M - s s^T / M^2 ; fully coalesced over stored tiles ----------------
// grid: b*192 + t3*64 + blk  (each (b,t3) tile = 64 blocks x 256 thr = 16384 elems)
__global__ __launch_bounds__(256)
void k_asm(const float* __restrict__ P, const float* __restrict__ s,
           float* __restrict__ cov) {
  int gid = blockIdx.x;
  int b = gid / 192;
  int rem = gid - b * 192;
  int t3 = rem >> 6;
  int loc = (rem & 63) * 256 + threadIdx.x;
  int row = loc >> 7, col = loc & 127;
  int tm = (t3 == 2) ? 1 : 0;
  int tn = (t3 >= 1) ? 1 : 0;
  int r = tm * 128 + row, c = tn * 128 + col;
  const float invM = 1.0f / 12544.0f;
  float g = 0.f;
#pragma unroll
  for (int sp = 0; sp < SPLITK; ++sp)
    g += P[((size_t)(sp * NB + b) * 3 + t3) * 16384 + loc];
  float v = g * invM - s[b * NC + r] * s[b * NC + c] * (invM * invM);
  cov[(size_t)b * 65536 + r * 256 + c] = v;
  if (t3 == 1) cov[(size_t)b * 65536 + c * 256 + r] = v;   // quadrant (1,0)
}

// ---------------- An = cov/normA (bf16); Z0 = 1.5I - 0.5 An (bf16) ----------------
__global__ void k_anzy(const float* __restrict__ cov, const float* __restrict__ nrm,
                       unsigned short* __restrict__ An, unsigned short* __restrict__ Z) {
  int i = blockIdx.x * 256 + threadIdx.x;
  int b = i >> 16;
  int rc = i & 65535;
  int r = rc >> 8, c = rc & 255;
  float a = cov[i] / nrm[b];
  An[i] = f2bf(a);
  Z[i]  = f2bf((r == c ? 1.5f : 0.0f) - 0.5f * a);
}

// ---------------- NS matmul, single-stage K=256: C = A*B (B sym -> NT). MODE1: 1.5I-0.5AB ----------------
template <int MODE>
__global__ __launch_bounds__(256)
void k_ns(const unsigned short* __restrict__ A0, const unsigned short* __restrict__ B0,
          unsigned short* __restrict__ C0,
          const unsigned short* __restrict__ A1, const unsigned short* __restrict__ B1,
          unsigned short* __restrict__ C1) {
  const unsigned short* A  = blockIdx.y ? A1 : A0;
  const unsigned short* Bm = blockIdx.y ? B1 : B0;
  unsigned short* Cm       = blockIdx.y ? C1 : C0;
  int bid = blockIdx.x;
  int tile = bid & 15, b = bid >> 4;
  int tm = tile >> 2, tn = tile & 3;

  __shared__ __align__(16) unsigned short As[64 * 256];
  __shared__ __align__(16) unsigned short Bs[64 * 256];

  int tid = threadIdx.x, lane = tid & 63, w = tid >> 6;
  int wm = w >> 1, wn = w & 1;
  int fr = lane & 15, kg = lane >> 4;

  const unsigned short* Ab = A  + (size_t)b * 65536 + (size_t)(tm * 64) * 256;
  const unsigned short* Bb = Bm + (size_t)b * 65536 + (size_t)(tn * 64) * 256;
  int r8 = tid >> 5;                       // 0..7
  size_t srcoff = (size_t)r8 * 256 + (size_t)((tid & 31) ^ r8) * 8;
  char* AsW = (char*)As + (size_t)(w * 2) * 512;
  char* BsW = (char*)Bs + (size_t)(w * 2) * 512;
#pragma unroll
  for (int j = 0; j < 8; ++j) {
    GLD16(Ab + srcoff + (size_t)j * 8 * 256, AsW + (size_t)j * 8 * 512);
    GLD16(Bb + srcoff + (size_t)j * 8 * 256, BsW + (size_t)j * 8 * 512);
  }
  __syncthreads();

  const char* Asc = (const char*)As;
  const char* Bsc = (const char*)Bs;
  f32x4 acc[2][2];
#pragma unroll
  for (int i = 0; i < 2; ++i)
#pragma unroll
    for (int j = 0; j < 2; ++j) acc[i][j] = f32x4{0.f, 0.f, 0.f, 0.f};

  int f7 = fr & 7;
#pragma unroll
  for (int kk = 0; kk < 8; ++kk) {
    bf16x8 av[2], bv[2];
#pragma unroll
    for (int fm = 0; fm < 2; ++fm) {
      int row = wm * 32 + fm * 16 + fr;
      av[fm] = *(const bf16x8*)(Asc + row * 512 + ((((kk << 2) | kg) ^ f7) << 4));
    }
#pragma unroll
    for (int fn = 0; fn < 2; ++fn) {
      int row = wn * 32 + fn * 16 + fr;
      bv[fn] = *(const bf16x8*)(Bsc + row * 512 + ((((kk << 2) | kg) ^ f7) << 4));
    }
#pragma unroll
    for (int fm = 0; fm < 2; ++fm)
#pragma unroll
      for (int fn = 0; fn < 2; ++fn)
        acc[fm][fn] = __builtin_amdgcn_mfma_f32_16x16x32_bf16(av[fm], bv[fn], acc[fm][fn], 0, 0, 0);
  }

  unsigned short* Cb = Cm + (size_t)b * ND * ND;
#pragma unroll
  for (int fm = 0; fm < 2; ++fm)
#pragma unroll
    for (int fn = 0; fn < 2; ++fn)
#pragma unroll
      for (int ri = 0; ri < 4; ++ri) {
        int row = tm * 64 + wm * 32 + fm * 16 + kg * 4 + ri;
        int col = tn * 64 + wn * 32 + fn * 16 + fr;
        float v = acc[fm][fn][ri];
        if (MODE == 1) v = (row == col ? 1.5f : 0.0f) - 0.5f * v;
        Cb[row * ND + col] = f2bf(v);
      }
}

// ---------------- final: out = triuvec(Y @ ZY) * sqrt(normA), single-stage K=256 ----------------
__global__ __launch_bounds__(256)
void k_final(const unsigned short* __restrict__ Y, const unsigned short* __restrict__ ZY,
             const float* __restrict__ nrm, float* __restrict__ out) {
  const int tmv[10] = {0, 1, 2, 3, 5, 6, 7, 10, 11, 15};  // upper-tri 64x64 tiles
  int bid = blockIdx.x;
  int t = bid % 10, b = bid / 10;
  int tile = tmv[t];
  int tm = tile >> 2, tn = tile & 3;

  __shared__ __align__(16) unsigned short As[64 * 256];
  __shared__ __align__(16) unsigned short Bs[64 * 256];

  int tid = threadIdx.x, lane = tid & 63, w = tid >> 6;
  int wm = w >> 1, wn = w & 1;
  int fr = lane & 15, kg = lane >> 4;

  const unsigned short* Ab = Y  + (size_t)b * 65536 + (size_t)(tm * 64) * 256;
  const unsigned short* Bb = ZY + (size_t)b * 65536 + (size_t)(tn * 64) * 256;
  int r8 = tid >> 5;
  size_t srcoff = (size_t)r8 * 256 + (size_t)((tid & 31) ^ r8) * 8;
  char* AsW = (char*)As + (size_t)(w * 2) * 512;
  char* BsW = (char*)Bs + (size_t)(w * 2) * 512;
#pragma unroll
  for (int j = 0; j < 8; ++j) {
    GLD16(Ab + srcoff + (size_t)j * 8 * 256, AsW + (size_t)j * 8 * 512);
    GLD16(Bb + srcoff + (size_t)j * 8 * 256, BsW + (size_t)j * 8 * 512);
  }
  __syncthreads();

  const char* Asc = (const char*)As;
  const char* Bsc = (const char*)Bs;
  f32x4 acc[2][2];
#pragma unroll
  for (int i = 0; i < 2; ++i)
#pragma unroll
    for (int j = 0; j < 2; ++j) acc[i][j] = f32x4{0.f, 0.f, 0.f, 0.f};

  int f7 = fr & 7;
#pragma unroll
  for (int kk = 0; kk < 8; ++kk) {
    bf16x8 av[2], bv[2];
#pragma unroll
    for (int fm = 0; fm < 2; ++fm) {
      int row = wm * 32 + fm * 16 + fr;
      av[fm] = *(const bf16x8*)(Asc + row * 512 + ((((kk << 2) | kg) ^ f7) << 4));
    }
#pragma unroll
    for (int fn = 0; fn < 2; ++fn) {
      int row = wn * 32 + fn * 16 + fr;
      bv[fn] = *(const bf16x8*)(Bsc + row * 512 + ((((kk << 2) | kg) ^ f7) << 4));
    }
#pragma unroll
    for (int fm = 0; fm < 2; ++fm)
#pragma unroll
      for (int fn = 0; fn < 2; ++fn)
        acc[fm][fn] = __builtin_amdgcn_mfma_f32_16x16x32_bf16(av[fm], bv[fn], acc[fm][fn], 0, 0, 0);
  }

  float sc = sqrtf(nrm[b]);
#pragma unroll
  for (int fm = 0; fm < 2; ++fm)
#pragma unroll
    for (int fn = 0; fn < 2; ++fn)
#pragma unroll
      for (int ri = 0; ri < 4; ++ri) {
        int row = tm * 64 + wm * 32 + fm * 16 + kg * 4 + ri;
        int col = tn * 64 + wn * 32 + fn * 16 + fr;
        if (row <= col) {
          int idx = row * ND - (row * (row - 1)) / 2 + (col - row);
          out[(size_t)b * NTRI + idx] = acc[fm][fn][ri] * sc;
        }
      }
}

extern "C" void kernel_launch(void* const* d_in, const int* in_sizes, int n_in,
                              void* d_out, int out_size, void* d_ws, size_t ws_size,
                              hipStream_t stream) {
  const float* x   = (const float*)d_in[0];
  const float* raw = (const float*)d_in[1];
  float* out = (float*)d_out;
  char* ws = (char*)d_ws;

  const size_t Z_OFF   = 0;
  const size_t S_OFF   = Z_OFF + (size_t)NB * NC * NM * 2;            // 102,760,448
  const size_t P_OFF   = S_OFF + (size_t)NB * NC * 4;                 // + 16,384
  const size_t COV_OFF = P_OFF + (size_t)SPLITK * NB * 3 * 16384 * 4; // + 50,331,648
  const size_t NA_OFF  = COV_OFF + (size_t)NB * ND * ND * 4;          // + 4,194,304
  const size_t AN_OFF  = NA_OFF + 64;
  const size_t MATB    = (size_t)NB * ND * ND * 2;                    // 2,097,152
  const size_t Y_OFF   = AN_OFF + MATB;
  const size_t ZM_OFF  = Y_OFF + MATB;
  const size_t ZY_OFF  = ZM_OFF + MATB;
  const size_t Y2_OFF  = ZY_OFF + MATB;
  const size_t Z2_OFF  = Y2_OFF + MATB;

  unsigned short* z   = (unsigned short*)(ws + Z_OFF);
  float* ssum = (float*)(ws + S_OFF);
  float* P    = (float*)(ws + P_OFF);
  float* cov  = (float*)(ws + COV_OFF);
  float* nrm  = (float*)(ws + NA_OFF);
  unsigned short* An  = (unsigned short*)(ws + AN_OFF);
  unsigned short* Yb  = (unsigned short*)(ws + Y_OFF);
  unsigned short* Zb  = (unsigned short*)(ws + ZM_OFF);
  unsigned short* ZYb = (unsigned short*)(ws + ZY_OFF);
  unsigned short* Y2b = (unsigned short*)(ws + Y2_OFF);
  unsigned short* Z2b = (unsigned short*)(ws + Z2_OFF);

  hipMemsetAsync(nrm, 0, 64, stream);
  k_z<<<NB * NC, 256, 0, stream>>>(x, raw, z, ssum, out + ATT_OUT_OFF);
  k_cov<<<NB * 3 * SPLITK, 256, 0, stream>>>(z, P);
  k_trace<<<NB, 256, 0, stream>>>(P, ssum, nrm);
  k_asm<<<NB * 3 * 64, 256, 0, stream>>>(P, ssum, cov);
  k_anzy<<<NB * ND * ND / 256, 256, 0, stream>>>(cov, nrm, An, Zb);

  // Y1 = An @ ZY0   (ZY0 stored in Zb)
  k_ns<0><<<dim3(256, 1), 256, 0, stream>>>(An, Zb, Yb, An, Zb, Yb);

  unsigned short *Yc = Yb, *Zc = Zb, *Yn = Y2b, *Zn = Z2b;
  for (int it = 0; it < 3; ++it) {
    k_ns<1><<<dim3(256, 1), 256, 0, stream>>>(Zc, Yc, ZYb, Zc, Yc, ZYb);      // ZY = 1.5I - 0.5 Z@Y
    k_ns<0><<<dim3(256, 2), 256, 0, stream>>>(Yc, ZYb, Yn, ZYb, Zc, Zn);      // Y'=Y@ZY ; Z'=ZY@Z
    unsigned short* t;
    t = Yc; Yc = Yn; Yn = t;
    t = Zc; Zc = Zn; Zn = t;
  }
  k_ns<1><<<dim3(256, 1), 256, 0, stream>>>(Zc, Yc, ZYb, Zc, Yc, ZYb);        // final ZY
  k_final<<<160, 256, 0, stream>>>(Yc, ZYb, nrm, out);                        // triuvec(Y@ZY)*sqrt(normA)
}

// Round 13
// 183.429 us; speedup vs baseline: 1.3662x; 1.0829x over previous
//
#include <hip/hip_runtime.h>

#define NB 16
#define NC 256
#define NHW 784
#define NATN 16
#define NM 12544          // 16*784
#define ND 256
#define NTRI 32896        // 256*257/2
#define ATT_OUT_OFF 526336
#define SPLITK 16

typedef float f32x4 __attribute__((ext_vector_type(4)));
typedef short bf16x8 __attribute__((ext_vector_type(8)));
typedef unsigned short us8 __attribute__((ext_vector_type(8)));

static __device__ __forceinline__ unsigned short f2bf(float f) {
  unsigned int u = __float_as_uint(f);
  u = (u + 0x7FFFu + ((u >> 16) & 1u)) >> 16;   // RNE
  return (unsigned short)u;
}

#define GLD16(g, l) __builtin_amdgcn_global_load_lds(                      \
    (const __attribute__((address_space(1))) void*)(g),                    \
    (__attribute__((address_space(3))) void*)(l), 16, 0, 0)

// ---------------- att = sigmoid(raw)+eps, computed ONCE (0.8 MB) ----------------
__global__ __launch_bounds__(256)
void k_attn(const float* __restrict__ raw, float* __restrict__ att,
            float* __restrict__ out_att) {
  int i = blockIdx.x * 256 + threadIdx.x;    // 784 blocks * 256 = 200704 exactly
  float v = raw[i];
  float a = 1.0f / (1.0f + __expf(-v)) + 1e-12f;
  att[i] = a;
  out_att[i] = a;
}

// ---------------- z = att * x (bf16) + row sums; write-bound, all lanes active ----------------
__global__ __launch_bounds__(256)
void k_z(const float* __restrict__ x, const float* __restrict__ att,
         unsigned short* __restrict__ z, float* __restrict__ s) {
  int bc = blockIdx.x;                 // b*256 + c
  int b  = bc >> 8;
  int t  = threadIdx.x;
  const float* xr = x + (size_t)bc * NHW;
  const float* ar = att + (size_t)b * NATN * NHW;
  unsigned short* zr = z + (size_t)bc * NM;
  float sum = 0.f;
  for (int ch = t; ch < 1568; ch += 256) {   // 1568 = 16 a * 98 chunks of 8
    int a = ch / 98;
    int hw0 = (ch - a * 98) * 8;
    float4 x0 = *(const float4*)&xr[hw0];
    float4 x1 = *(const float4*)&xr[hw0 + 4];
    const float* ap = ar + a * NHW + hw0;
    float4 a0 = *(const float4*)&ap[0];
    float4 a1 = *(const float4*)&ap[4];
    float v0 = a0.x * x0.x, v1 = a0.y * x0.y, v2 = a0.z * x0.z, v3 = a0.w * x0.w;
    float v4 = a1.x * x1.x, v5 = a1.y * x1.y, v6 = a1.z * x1.z, v7 = a1.w * x1.w;
    us8 zv;
    zv[0] = f2bf(v0); zv[1] = f2bf(v1); zv[2] = f2bf(v2); zv[3] = f2bf(v3);
    zv[4] = f2bf(v4); zv[5] = f2bf(v5); zv[6] = f2bf(v6); zv[7] = f2bf(v7);
    *(us8*)&zr[a * NHW + hw0] = zv;
    sum += v0 + v1 + v2 + v3 + v4 + v5 + v6 + v7;
  }
  for (int off = 32; off; off >>= 1) sum += __shfl_down(sum, off, 64);
  __shared__ float red[4];
  if ((t & 63) == 0) red[t >> 6] = sum;
  __syncthreads();
  if (t == 0) s[bc] = red[0] + red[1] + red[2] + red[3];
}

// ---------------- cov GEMM: P[split][b][t3] += z_tile * z_tile^T ----------------
__global__ __launch_bounds__(256)
void k_cov(const unsigned short* __restrict__ z, float* __restrict__ P) {
  int bid = blockIdx.x;
  int split = bid & 15;
  int t3 = (bid >> 4) % 3;
  int b = bid / 48;
  int tm = (t3 == 2) ? 1 : 0;
  int tn = (t3 >= 1) ? 1 : 0;

  __shared__ __align__(16) unsigned short As[128 * 64];
  __shared__ __align__(16) unsigned short Bs[128 * 64];

  int tid = threadIdx.x;
  int lane = tid & 63, w = tid >> 6;
  int wm = w >> 1, wn = w & 1;
  int fr = lane & 15, kg = lane >> 4;

  const unsigned short* zb = z + (size_t)b * NC * NM;
  int col8 = ((tid & 7) ^ ((tid >> 3) & 7)) * 8;       // source pre-swizzle
  const unsigned short* ab = zb + (size_t)(tm * 128 + (tid >> 3)) * NM + col8;
  const unsigned short* bb = zb + (size_t)(tn * 128 + (tid >> 3)) * NM + col8;

  f32x4 acc[4][4];
#pragma unroll
  for (int i = 0; i < 4; ++i)
#pragma unroll
    for (int j = 0; j < 4; ++j) acc[i][j] = f32x4{0.f, 0.f, 0.f, 0.f};

  int ktiles = 12 + (split < 4 ? 1 : 0);
  int k0 = (split * 12 + (split < 4 ? split : 4)) * 64;
  char* AsB = (char*)As + (size_t)w * 1024;
  char* BsB = (char*)Bs + (size_t)w * 1024;
  const char* Asc = (const char*)As;
  const char* Bsc = (const char*)Bs;

  for (int kt = 0; kt < ktiles; ++kt) {
    int kb = k0 + kt * 64;
#pragma unroll
    for (int r = 0; r < 4; ++r) GLD16(ab + (size_t)r * 32 * NM + kb, AsB + r * 4096);
#pragma unroll
    for (int r = 0; r < 4; ++r) GLD16(bb + (size_t)r * 32 * NM + kb, BsB + r * 4096);
    __syncthreads();
#pragma unroll
    for (int kk = 0; kk < 2; ++kk) {
      bf16x8 av[4], bv[4];
      int swz = (fr & 7) << 4;
#pragma unroll
      for (int fm = 0; fm < 4; ++fm)
        av[fm] = *(const bf16x8*)(Asc + (wm * 64 + fm * 16 + fr) * 128 + ((kk * 64 + kg * 16) ^ swz));
#pragma unroll
      for (int fn = 0; fn < 4; ++fn)
        bv[fn] = *(const bf16x8*)(Bsc + (wn * 64 + fn * 16 + fr) * 128 + ((kk * 64 + kg * 16) ^ swz));
#pragma unroll
      for (int fm = 0; fm < 4; ++fm)
#pragma unroll
        for (int fn = 0; fn < 4; ++fn)
          acc[fm][fn] = __builtin_amdgcn_mfma_f32_16x16x32_bf16(av[fm], bv[fn], acc[fm][fn], 0, 0, 0);
    }
    __syncthreads();
  }

  float* Pb = P + ((size_t)(split * NB + b) * 3 + t3) * 16384;
#pragma unroll
  for (int fm = 0; fm < 4; ++fm)
#pragma unroll
    for (int fn = 0; fn < 4; ++fn)
#pragma unroll
      for (int ri = 0; ri < 4; ++ri) {
        int row = wm * 64 + fm * 16 + kg * 4 + ri;   // tile-local
        int col = wn * 64 + fn * 16 + fr;
        Pb[row * 128 + col] = acc[fm][fn][ri];
      }
}

// ---------------- trace: nrm[b] = sum_d [ (sum_sp Pdiag)/M - s_d^2/M^2 ]  (no atomics) ----------------
__global__ __launch_bounds__(256)
void k_trace(const float* __restrict__ P, const float* __restrict__ s,
             float* __restrict__ nrm) {
  int b = blockIdx.x, t = threadIdx.x;
  int t3 = (t < 128) ? 0 : 2;
  int loc = (t & 127) * 129;
  const float invM = 1.0f / 12544.0f;
  float g = 0.f;
#pragma unroll
  for (int sp = 0; sp < SPLITK; ++sp)
    g += P[((size_t)(sp * NB + b) * 3 + t3) * 16384 + loc];
  float sd = s[b * NC + t];
  float v = g * invM - sd * sd * (invM * invM);
  for (int off = 32; off; off >>= 1) v += __shfl_down(v, off, 64);
  __shared__ float red[4];
  if ((t & 63) == 0) red[t >> 6] = v;
  __syncthreads();
  if (t == 0) nrm[b] = red[0] + red[1] + red[2] + red[3];
}

// ---------------- cov = (sum P)/M - s s^T / M^2 ; fully coalesced over stored tiles ----------------
__global__ __launch_bounds__(256)
void k_asm(const float* __restrict__ P, const float* __restrict__ s,
           float* __restrict__ cov) {
  int gid = blockIdx.x;
  int b = gid / 192;
  int rem = gid - b * 192;
  int t3 = rem >> 6;
  int loc = (rem & 63) * 256 + threadIdx.x;
  int row = loc >> 7, col = loc & 127;
  int tm = (t3 == 2) ? 1 : 0;
  int tn = (t3 >= 1) ? 1 : 0;
  int r = tm * 128 + row, c = tn * 128 + col;
  const float invM = 1.0f / 12544.0f;
  float g = 0.f;
#pragma unroll
  for (int sp = 0; sp < SPLITK; ++sp)
    g += P[((size_t)(sp * NB + b) * 3 + t3) * 16384 + loc];
  float v = g * invM - s[b * NC + r] * s[b * NC + c] * (invM * invM);
  cov[(size_t)b * 65536 + r * 256 + c] = v;
  if (t3 == 1) cov[(size_t)b * 65536 + c * 256 + r] = v;   // quadrant (1,0)
}

// ---------------- An = cov/normA (bf16); Z0 = 1.5I - 0.5 An (bf16) ----------------
__global__ void k_anzy(const float* __restrict__ cov, const float* __restrict__ nrm,
                       unsigned short* __restrict__ An, unsigned short* __restrict__ Z) {
  int i = blockIdx.x * 256 + threadIdx.x;
  int b = i >> 16;
  int rc = i & 65535;
  int r = rc >> 8, c = rc & 255;
  float a = cov[i] / nrm[b];
  An[i] = f2bf(a);
  Z[i]  = f2bf((r == c ? 1.5f : 0.0f) - 0.5f * a);
}

// ---------------- NS matmul, single-stage K=256: C = A*B (B sym -> NT). MODE1: 1.5I-0.5AB ----------------
template <int MODE>
__global__ __launch_bounds__(256)
void k_ns(const unsigned short* __restrict__ A0, const unsigned short* __restrict__ B0,
          unsigned short* __restrict__ C0,
          const unsigned short* __restrict__ A1, const unsigned short* __restrict__ B1,
          unsigned short* __restrict__ C1) {
  const unsigned short* A  = blockIdx.y ? A1 : A0;
  const unsigned short* Bm = blockIdx.y ? B1 : B0;
  unsigned short* Cm       = blockIdx.y ? C1 : C0;
  int bid = blockIdx.x;
  int tile = bid & 15, b = bid >> 4;
  int tm = tile >> 2, tn = tile & 3;

  __shared__ __align__(16) unsigned short As[64 * 256];
  __shared__ __align__(16) unsigned short Bs[64 * 256];

  int tid = threadIdx.x, lane = tid & 63, w = tid >> 6;
  int wm = w >> 1, wn = w & 1;
  int fr = lane & 15, kg = lane >> 4;

  const unsigned short* Ab = A  + (size_t)b * 65536 + (size_t)(tm * 64) * 256;
  const unsigned short* Bb = Bm + (size_t)b * 65536 + (size_t)(tn * 64) * 256;
  int r8 = tid >> 5;                       // 0..7
  size_t srcoff = (size_t)r8 * 256 + (size_t)((tid & 31) ^ r8) * 8;
  char* AsW = (char*)As + (size_t)(w * 2) * 512;
  char* BsW = (char*)Bs + (size_t)(w * 2) * 512;
#pragma unroll
  for (int j = 0; j < 8; ++j) {
    GLD16(Ab + srcoff + (size_t)j * 8 * 256, AsW + (size_t)j * 8 * 512);
    GLD16(Bb + srcoff + (size_t)j * 8 * 256, BsW + (size_t)j * 8 * 512);
  }
  __syncthreads();

  const char* Asc = (const char*)As;
  const char* Bsc = (const char*)Bs;
  f32x4 acc[2][2];
#pragma unroll
  for (int i = 0; i < 2; ++i)
#pragma unroll
    for (int j = 0; j < 2; ++j) acc[i][j] = f32x4{0.f, 0.f, 0.f, 0.f};

  int f7 = fr & 7;
#pragma unroll
  for (int kk = 0; kk < 8; ++kk) {
    bf16x8 av[2], bv[2];
#pragma unroll
    for (int fm = 0; fm < 2; ++fm) {
      int row = wm * 32 + fm * 16 + fr;
      av[fm] = *(const bf16x8*)(Asc + row * 512 + ((((kk << 2) | kg) ^ f7) << 4));
    }
#pragma unroll
    for (int fn = 0; fn < 2; ++fn) {
      int row = wn * 32 + fn * 16 + fr;
      bv[fn] = *(const bf16x8*)(Bsc + row * 512 + ((((kk << 2) | kg) ^ f7) << 4));
    }
#pragma unroll
    for (int fm = 0; fm < 2; ++fm)
#pragma unroll
      for (int fn = 0; fn < 2; ++fn)
        acc[fm][fn] = __builtin_amdgcn_mfma_f32_16x16x32_bf16(av[fm], bv[fn], acc[fm][fn], 0, 0, 0);
  }

  unsigned short* Cb = Cm + (size_t)b * ND * ND;
#pragma unroll
  for (int fm = 0; fm < 2; ++fm)
#pragma unroll
    for (int fn = 0; fn < 2; ++fn)
#pragma unroll
      for (int ri = 0; ri < 4; ++ri) {
        int row = tm * 64 + wm * 32 + fm * 16 + kg * 4 + ri;
        int col = tn * 64 + wn * 32 + fn * 16 + fr;
        float v = acc[fm][fn][ri];
        if (MODE == 1) v = (row == col ? 1.5f : 0.0f) - 0.5f * v;
        Cb[row * ND + col] = f2bf(v);
      }
}

// ---------------- final: out = triuvec(Y @ ZY) * sqrt(normA), single-stage K=256 ----------------
__global__ __launch_bounds__(256)
void k_final(const unsigned short* __restrict__ Y, const unsigned short* __restrict__ ZY,
             const float* __restrict__ nrm, float* __restrict__ out) {
  const int tmv[10] = {0, 1, 2, 3, 5, 6, 7, 10, 11, 15};  // upper-tri 64x64 tiles
  int bid = blockIdx.x;
  int t = bid % 10, b = bid / 10;
  int tile = tmv[t];
  int tm = tile >> 2, tn = tile & 3;

  __shared__ __align__(16) unsigned short As[64 * 256];
  __shared__ __align__(16) unsigned short Bs[64 * 256];

  int tid = threadIdx.x, lane = tid & 63, w = tid >> 6;
  int wm = w >> 1, wn = w & 1;
  int fr = lane & 15, kg = lane >> 4;

  const unsigned short* Ab = Y  + (size_t)b * 65536 + (size_t)(tm * 64) * 256;
  const unsigned short* Bb = ZY + (size_t)b * 65536 + (size_t)(tn * 64) * 256;
  int r8 = tid >> 5;
  size_t srcoff = (size_t)r8 * 256 + (size_t)((tid & 31) ^ r8) * 8;
  char* AsW = (char*)As + (size_t)(w * 2) * 512;
  char* BsW = (char*)Bs + (size_t)(w * 2) * 512;
#pragma unroll
  for (int j = 0; j < 8; ++j) {
    GLD16(Ab + srcoff + (size_t)j * 8 * 256, AsW + (size_t)j * 8 * 512);
    GLD16(Bb + srcoff + (size_t)j * 8 * 256, BsW + (size_t)j * 8 * 512);
  }
  __syncthreads();

  const char* Asc = (const char*)As;
  const char* Bsc = (const char*)Bs;
  f32x4 acc[2][2];
#pragma unroll
  for (int i = 0; i < 2; ++i)
#pragma unroll
    for (int j = 0; j < 2; ++j) acc[i][j] = f32x4{0.f, 0.f, 0.f, 0.f};

  int f7 = fr & 7;
#pragma unroll
  for (int kk = 0; kk < 8; ++kk) {
    bf16x8 av[2], bv[2];
#pragma unroll
    for (int fm = 0; fm < 2; ++fm) {
      int row = wm * 32 + fm * 16 + fr;
      av[fm] = *(const bf16x8*)(Asc + row * 512 + ((((kk << 2) | kg) ^ f7) << 4));
    }
#pragma unroll
    for (int fn = 0; fn < 2; ++fn) {
      int row = wn * 32 + fn * 16 + fr;
      bv[fn] = *(const bf16x8*)(Bsc + row * 512 + ((((kk << 2) | kg) ^ f7) << 4));
    }
#pragma unroll
    for (int fm = 0; fm < 2; ++fm)
#pragma unroll
      for (int fn = 0; fn < 2; ++fn)
        acc[fm][fn] = __builtin_amdgcn_mfma_f32_16x16x32_bf16(av[fm], bv[fn], acc[fm][fn], 0, 0, 0);
  }

  float sc = sqrtf(nrm[b]);
#pragma unroll
  for (int fm = 0; fm < 2; ++fm)
#pragma unroll
    for (int fn = 0; fn < 2; ++fn)
#pragma unroll
      for (int ri = 0; ri < 4; ++ri) {
        int row = tm * 64 + wm * 32 + fm * 16 + kg * 4 + ri;
        int col = tn * 64 + wn * 32 + fn * 16 + fr;
        if (row <= col) {
          int idx = row * ND - (row * (row - 1)) / 2 + (col - row);
          out[(size_t)b * NTRI + idx] = acc[fm][fn][ri] * sc;
        }
      }
}

extern "C" void kernel_launch(void* const* d_in, const int* in_sizes, int n_in,
                              void* d_out, int out_size, void* d_ws, size_t ws_size,
                              hipStream_t stream) {
  const float* x   = (const float*)d_in[0];
  const float* raw = (const float*)d_in[1];
  float* out = (float*)d_out;
  char* ws = (char*)d_ws;

  const size_t Z_OFF   = 0;
  const size_t S_OFF   = Z_OFF + (size_t)NB * NC * NM * 2;            // 102,760,448
  const size_t P_OFF   = S_OFF + (size_t)NB * NC * 4;                 // + 16,384
  const size_t COV_OFF = P_OFF + (size_t)SPLITK * NB * 3 * 16384 * 4; // + 50,331,648
  const size_t NA_OFF  = COV_OFF + (size_t)NB * ND * ND * 4;          // + 4,194,304
  const size_t AN_OFF  = NA_OFF + 64;
  const size_t MATB    = (size_t)NB * ND * ND * 2;                    // 2,097,152
  const size_t Y_OFF   = AN_OFF + MATB;
  const size_t ZM_OFF  = Y_OFF + MATB;
  const size_t ZY_OFF  = ZM_OFF + MATB;
  const size_t Y2_OFF  = ZY_OFF + MATB;
  const size_t Z2_OFF  = Y2_OFF + MATB;
  const size_t ATT_OFF = Z2_OFF + MATB;                               // + 802,816

  unsigned short* z   = (unsigned short*)(ws + Z_OFF);
  float* ssum = (float*)(ws + S_OFF);
  float* P    = (float*)(ws + P_OFF);
  float* cov  = (float*)(ws + COV_OFF);
  float* nrm  = (float*)(ws + NA_OFF);
  unsigned short* An  = (unsigned short*)(ws + AN_OFF);
  unsigned short* Yb  = (unsigned short*)(ws + Y_OFF);
  unsigned short* Zb  = (unsigned short*)(ws + ZM_OFF);
  unsigned short* ZYb = (unsigned short*)(ws + ZY_OFF);
  unsigned short* Y2b = (unsigned short*)(ws + Y2_OFF);
  unsigned short* Z2b = (unsigned short*)(ws + Z2_OFF);
  float* att  = (float*)(ws + ATT_OFF);

  k_attn<<<784, 256, 0, stream>>>(raw, att, out + ATT_OUT_OFF);
  k_z<<<NB * NC, 256, 0, stream>>>(x, att, z, ssum);
  k_cov<<<NB * 3 * SPLITK, 256, 0, stream>>>(z, P);
  k_trace<<<NB, 256, 0, stream>>>(P, ssum, nrm);
  k_asm<<<NB * 3 * 64, 256, 0, stream>>>(P, ssum, cov);
  k_anzy<<<NB * ND * ND / 256, 256, 0, stream>>>(cov, nrm, An, Zb);

  // Y1 = An @ ZY0   (ZY0 stored in Zb)
  k_ns<0><<<dim3(256, 1), 256, 0, stream>>>(An, Zb, Yb, An, Zb, Yb);

  unsigned short *Yc = Yb, *Zc = Zb, *Yn = Y2b, *Zn = Z2b;
  for (int it = 0; it < 3; ++it) {
    k_ns<1><<<dim3(256, 1), 256, 0, stream>>>(Zc, Yc, ZYb, Zc, Yc, ZYb);      // ZY = 1.5I - 0.5 Z@Y
    k_ns<0><<<dim3(256, 2), 256, 0, stream>>>(Yc, ZYb, Yn, ZYb, Zc, Zn);      // Y'=Y@ZY ; Z'=ZY@Z
    unsigned short* t;
    t = Yc; Yc = Yn; Yn = t;
    t = Zc; Zc = Zn; Zn = t;
  }
  k_ns<1><<<dim3(256, 1), 256, 0, stream>>>(Zc, Yc, ZYb, Zc, Yc, ZYb);        // final ZY
  k_final<<<160, 256, 0, stream>>>(Yc, ZYb, nrm, out);                        // triuvec(Y@ZY)*sqrt(normA)
}